// Round 2
// baseline (876.654 us; speedup 1.0000x reference)
//
#include <hip/hip_runtime.h>

// ---------------------------------------------------------------------------
// SharedAtomModel: pooled-embedding encoder -> sparse dictionary top-k -> heads
//
// Sizes: B=1024 S=32 D=512 DICT=16384 TOPK=32
// Outputs (fp32, flat): [1024x16][1024x6][1024x16][1024x6][4 x 1024x16384]
//
// R4 = R3 with two harness-safety fixes:
//  - hipMemsetAsync replaced by zero_kernel (graph-capture-safe zero fill).
//  - selvw/seliw moved into the dead `hw` encoder buffer (workspace stays at
//    R2's proven 66 MB footprint; no growth).
// R3 recap:
//  - approx_gemm emits per-row-tile candidates (key<<16 | 16383-col) >= 2*sigma
//    instead of materializing the 128 MB dense fp16 approx matrix.
//  - combine_kernel also writes combined fp32 weights (router + 0.3*delta);
//    select's exact recompute gathers 2 KB/candidate instead of 4 KB.
//  - select_kernel: no zero-fill, no dense read; emits compact (idx,val) x32.
//  - Sparse region zeroed once at write peak; heads_kernel scatters 32/row.
//  - wcf/wrf/candg staging lives inside the 256 MB sparse output region,
//    overwritten by the zero fill afterward.
// ---------------------------------------------------------------------------

typedef _Float16 f16x8 __attribute__((ext_vector_type(8)));
typedef _Float16 f16x4 __attribute__((ext_vector_type(4)));
typedef float f32x4 __attribute__((ext_vector_type(4)));

#define OUT_SPARSE 45056
#define SPARSE_PER 16777216

#define ASYNC16(gp, lp) __builtin_amdgcn_global_load_lds(                      \
    (const __attribute__((address_space(1))) void*)(gp),                       \
    (__attribute__((address_space(3))) void*)(lp), 16, 0, 0)

__device__ inline float h2f(unsigned s) {
    _Float16 h = __builtin_bit_cast(_Float16, (unsigned short)(s & 0xFFFFu));
    return (float)h;
}

// ---------------- K1: pooled mean embedding (fp64 accumulate) --------------
__global__ __launch_bounds__(128) void pool_kernel(
    const int* __restrict__ ct, const int* __restrict__ nt,
    const float* __restrict__ emb, double* __restrict__ xout)
{
    const int row = blockIdx.x, s = blockIdx.y;
    const int tid = threadIdx.x;
    __shared__ int tk[32];
    const int* t = (s ? nt : ct) + row * 32;
    if (tid < 32) tk[tid] = t[tid];
    __syncthreads();
    const int d = tid * 4;
    double a0 = 0, a1 = 0, a2 = 0, a3 = 0;
    for (int i = 0; i < 32; ++i) {
        const float4 v = *(const float4*)(emb + (size_t)tk[i] * 512 + d);
        a0 += (double)v.x; a1 += (double)v.y; a2 += (double)v.z; a3 += (double)v.w;
    }
    double* o = xout + ((size_t)s * 1024 + row) * 512 + d;
    o[0] = a0 * 0.03125; o[1] = a1 * 0.03125; o[2] = a2 * 0.03125; o[3] = a3 * 0.03125;
}

// ---------------- K2/K3: fp64 encoder GEMM: C = f(A @ W^T + b) -------------
__global__ __launch_bounds__(256) void enc_gemm(
    const double* __restrict__ A, const float* __restrict__ W,
    const float* __restrict__ bias, double* __restrict__ C,
    _Float16* __restrict__ C16, int act)
{
    __shared__ double Ask[16][68];
    __shared__ double Wsk[16][68];
    const int tid = threadIdx.x;
    const int m0 = blockIdx.y * 64, n0 = blockIdx.x * 64;
    const int ty = tid >> 4, tx = tid & 15;
    const int r = tid >> 2, c4 = (tid & 3) * 4;
    double acc[4][4] = {};
    for (int k0 = 0; k0 < 512; k0 += 16) {
        const double4 av = *(const double4*)(A + (size_t)(m0 + r) * 512 + k0 + c4);
        const float4  wv = *(const float4*) (W + (size_t)(n0 + r) * 512 + k0 + c4);
        __syncthreads();
        Ask[c4 + 0][r] = av.x; Ask[c4 + 1][r] = av.y; Ask[c4 + 2][r] = av.z; Ask[c4 + 3][r] = av.w;
        Wsk[c4 + 0][r] = (double)wv.x; Wsk[c4 + 1][r] = (double)wv.y;
        Wsk[c4 + 2][r] = (double)wv.z; Wsk[c4 + 3][r] = (double)wv.w;
        __syncthreads();
#pragma unroll
        for (int k = 0; k < 16; ++k) {
            const double4 a = *(const double4*)&Ask[k][ty * 4];
            const double4 b = *(const double4*)&Wsk[k][tx * 4];
            const double aa[4] = {a.x, a.y, a.z, a.w};
            const double bb[4] = {b.x, b.y, b.z, b.w};
#pragma unroll
            for (int i = 0; i < 4; ++i)
#pragma unroll
                for (int j = 0; j < 4; ++j) acc[i][j] += aa[i] * bb[j];
        }
    }
#pragma unroll
    for (int i = 0; i < 4; ++i) {
        const int row = m0 + ty * 4 + i;
#pragma unroll
        for (int j = 0; j < 4; ++j) {
            const int col = n0 + tx * 4 + j;
            double v = acc[i][j] + (double)bias[col];
            if (act) v = v / (1.0 + exp(-v));   // silu
            C[(size_t)row * 512 + col] = v;
            if (C16) C16[(size_t)row * 512 + col] = (_Float16)v;
        }
    }
}

// ---------------- K4: combined fp16 + fp32 weights -------------------------
__global__ __launch_bounds__(256) void combine_kernel(
    const float* __restrict__ router, const float* __restrict__ cd,
    const float* __restrict__ rd, _Float16* __restrict__ wc,
    _Float16* __restrict__ wr, float* __restrict__ wcf,
    float* __restrict__ wrf)
{
    const size_t i = ((size_t)blockIdx.x * 256 + threadIdx.x) * 4;
    if (i >= (size_t)16384 * 512) return;
    const float4 r = *(const float4*)(router + i);
    const float4 c = *(const float4*)(cd + i);
    const float4 d = *(const float4*)(rd + i);
    const float4 fc = { r.x + 0.3f * c.x, r.y + 0.3f * c.y, r.z + 0.3f * c.z, r.w + 0.3f * c.w };
    const float4 fr = { r.x + 0.3f * d.x, r.y + 0.3f * d.y, r.z + 0.3f * d.z, r.w + 0.3f * d.w };
    f16x4 hc = { (_Float16)fc.x, (_Float16)fc.y, (_Float16)fc.z, (_Float16)fc.w };
    f16x4 hr = { (_Float16)fr.x, (_Float16)fr.y, (_Float16)fr.z, (_Float16)fr.w };
    *(f16x4*)(wc + i) = hc;
    *(f16x4*)(wr + i) = hr;
    *(float4*)(wcf + i) = fc;
    *(float4*)(wrf + i) = fr;
}

// ---------------- K5: fp16 MFMA approx GEMM + candidate emission -----------
// Per (row, n-tile): emit packed (key15<<16 | 16383-col) for |v| >= 2*sigma_tile
// into 32 slots (zero-padded). True top-32 of a row sits at >=2.9*sigma_row;
// losing one needs sigma_tile ~45% high (chi^2_128 tail ~1e-12) -> safe.
__global__ __launch_bounds__(256) void approx_gemm(
    const _Float16* __restrict__ P, const _Float16* __restrict__ Wc,
    const _Float16* __restrict__ Wr, unsigned* __restrict__ candg)
{
    __shared__ _Float16 ABs[8192];          // As = [0,4096), Bs = [4096,8192)
    __shared__ _Float16 Cst[128 * 128];
    __shared__ unsigned ecnt[128];
    _Float16* As = ABs;
    _Float16* Bs = ABs + 4096;

    const int tid = threadIdx.x;
    const int q = blockIdx.z;
    const int n0 = blockIdx.x * 128, m0 = blockIdx.y * 128;
    const _Float16* A = P + (size_t)(q >> 1) * 524288;
    const _Float16* B = (q & 1) ? Wr : Wc;

    const int lane = tid & 63, w = tid >> 6;
    const int wm = w & 1, wn = w >> 1;
    const int lr = lane & 15, lk = lane >> 4;

    const int ch0 = w * 2, ch1 = w * 2 + 1;
    const int lrow = lane >> 2, lh = (lane & 3) * 8;
    const _Float16* Ag0 = A + (size_t)(m0 + ch0 * 16 + lrow) * 512 + lh;
    const _Float16* Ag1 = A + (size_t)(m0 + ch1 * 16 + lrow) * 512 + lh;
    const _Float16* Bg0 = B + (size_t)(n0 + ch0 * 16 + lrow) * 512 + lh;
    const _Float16* Bg1 = B + (size_t)(n0 + ch1 * 16 + lrow) * 512 + lh;
    _Float16* Al0 = As + ch0 * 512;
    _Float16* Al1 = As + ch1 * 512;
    _Float16* Bl0 = Bs + ch0 * 512;
    _Float16* Bl1 = Bs + ch1 * 512;

    const f32x4 zero = {0.f, 0.f, 0.f, 0.f};
    f32x4 acc[4][4];
#pragma unroll
    for (int i = 0; i < 4; ++i)
#pragma unroll
        for (int j = 0; j < 4; ++j) acc[i][j] = zero;

    for (int kt = 0; kt < 16; ++kt) {
        const int k0 = kt * 32;
        __syncthreads();                 // prev iter's ds_reads done
        ASYNC16(Ag0 + k0, Al0);
        ASYNC16(Ag1 + k0, Al1);
        ASYNC16(Bg0 + k0, Bl0);
        ASYNC16(Bg1 + k0, Bl1);
        __syncthreads();                 // implies vmcnt(0): LDS tiles ready
        f16x8 af[4], bf[4];
#pragma unroll
        for (int i = 0; i < 4; ++i) af[i] = *(const f16x8*)(As + (wm * 64 + i * 16 + lr) * 32 + lk * 8);
#pragma unroll
        for (int j = 0; j < 4; ++j) bf[j] = *(const f16x8*)(Bs + (wn * 64 + j * 16 + lr) * 32 + lk * 8);
#pragma unroll
        for (int i = 0; i < 4; ++i)
#pragma unroll
            for (int j = 0; j < 4; ++j)
                acc[i][j] = __builtin_amdgcn_mfma_f32_16x16x32_f16(af[i], bf[j], acc[i][j], 0, 0, 0);
    }
    __syncthreads();
    // C/D layout: col = lane&15, row = (lane>>4)*4 + reg  [m89-verified]
#pragma unroll
    for (int i = 0; i < 4; ++i)
#pragma unroll
        for (int j = 0; j < 4; ++j)
#pragma unroll
            for (int rr = 0; rr < 4; ++rr)
                Cst[(wm * 64 + i * 16 + lk * 4 + rr) * 128 + (wn * 64 + j * 16 + lr)] =
                    (_Float16)acc[i][j][rr];
    if (tid < 128) ecnt[tid] = 0;
    __syncthreads();

    // ---- candidate emission epilogue: 2 threads per row ----
    const int r = tid >> 1, h = tid & 1;
    const unsigned* cr = (const unsigned*)(Cst + r * 128 + h * 64);
    float ss = 0.f;
#pragma unroll
    for (int j = 0; j < 32; ++j) {
        const unsigned u = cr[j];
        const float f0 = h2f(u), f1 = h2f(u >> 16);
        ss = fmaf(f0, f0, fmaf(f1, f1, ss));
    }
    ss += __shfl_xor(ss, 1);
    const _Float16 hc = (_Float16)(2.0f * sqrtf(ss * (1.f / 128.f)));
    const unsigned cutk = (unsigned)__builtin_bit_cast(unsigned short, hc) & 0x7FFFu;
    unsigned* emit = (unsigned*)ABs;        // 128 rows x 32 slots = 16 KB
    const int colbase = n0 + h * 64;
#pragma unroll
    for (int j = 0; j < 32; ++j) {
        const unsigned u = cr[j];
        const unsigned k0 = u & 0x7FFFu, k1 = (u >> 16) & 0x7FFFu;
        if (k0 >= cutk && k0) {
            const unsigned pos = atomicAdd(&ecnt[r], 1u);
            if (pos < 32u) emit[r * 32 + pos] = (k0 << 16) | (unsigned)(16383 - (colbase + 2 * j));
        }
        if (k1 >= cutk && k1) {
            const unsigned pos = atomicAdd(&ecnt[r], 1u);
            if (pos < 32u) emit[r * 32 + pos] = (k1 << 16) | (unsigned)(16383 - (colbase + 2 * j + 1));
        }
    }
    __syncthreads();
    // zero-pad own half and store 64 B per thread
    {
        const unsigned c = min(ecnt[r], 32u);
#pragma unroll
        for (int s2 = 0; s2 < 16; ++s2) {
            const unsigned sl = (unsigned)(h * 16 + s2);
            if (sl >= c) emit[r * 32 + sl] = 0u;
        }
        unsigned* eg = candg + (((size_t)q * 1024 + m0 + r) * 128 + blockIdx.x) * 32;
        const uint4* e4 = (const uint4*)(emit + r * 32 + h * 16);
        uint4* g4 = (uint4*)(eg + h * 16);
        g4[0] = e4[0]; g4[1] = e4[1]; g4[2] = e4[2]; g4[3] = e4[3];
    }
}

// ---------------- K6: select + exact recompute (compact output) ------------
__global__ __launch_bounds__(256) void select_kernel(
    const double* __restrict__ pw, const float* __restrict__ wcf,
    const float* __restrict__ wrf, const unsigned* __restrict__ candg,
    const float* __restrict__ atoms, float* __restrict__ selvw,
    int* __restrict__ seliw, float* __restrict__ repw)
{
    constexpr int NCAP = 160, NRE = 64;
    const int row = blockIdx.x, q = blockIdx.y;
    const int pset = q >> 1;
    const int tid = threadIdx.x;

    __shared__ unsigned hist[1024];
    __shared__ unsigned pscan[256];
    __shared__ double prow[512];
    __shared__ unsigned cent[NCAP];
    __shared__ int r64i[NRE];
    __shared__ double cval[NRE];
    __shared__ float selv[32];
    __shared__ int seli[32];
    __shared__ int cnt, bstar;

    const double* prg = pw + ((size_t)pset * 1024 + row) * 512;
    const unsigned* crow = candg + ((size_t)q * 1024 + row) * 4096;

    for (int b = tid; b < 1024; b += 256) hist[b] = 0;
    if (tid == 0) { cnt = 0; bstar = -1; }
    if (tid < NRE) r64i[tid] = 0;
    prow[tid] = prg[tid];
    prow[tid + 256] = prg[tid + 256];

    uint4 cv[4];
#pragma unroll
    for (int p = 0; p < 4; ++p) cv[p] = ((const uint4*)crow)[p * 256 + tid];
    __syncthreads();

    // histogram of key>>5 (1024 bins); sentinel 0 entries skipped
#pragma unroll
    for (int p = 0; p < 4; ++p) {
        const unsigned ee[4] = {cv[p].x, cv[p].y, cv[p].z, cv[p].w};
#pragma unroll
        for (int e = 0; e < 4; ++e)
            if (ee[e]) atomicAdd(&hist[ee[e] >> 21], 1u);
    }
    __syncthreads();

    // suffix-scan from the top to find key threshold with >=64 above
    const unsigned h0 = hist[tid * 4], h1 = hist[tid * 4 + 1];
    const unsigned h2 = hist[tid * 4 + 2], h3 = hist[tid * 4 + 3];
    const unsigned l3 = h3, l2 = h2 + l3, l1 = h1 + l2, l0 = h0 + l1;
    pscan[tid] = l0;
    __syncthreads();
    for (int s = 1; s < 256; s <<= 1) {
        const unsigned v = (tid + s < 256) ? pscan[tid + s] : 0u;
        __syncthreads();
        pscan[tid] += v;
        __syncthreads();
    }
    {
        const unsigned above = (tid < 255) ? pscan[tid + 1] : 0u;
        int best = -1;
        if (l0 + above >= 64u) best = tid * 4;
        if (l1 + above >= 64u) best = tid * 4 + 1;
        if (l2 + above >= 64u) best = tid * 4 + 2;
        if (l3 + above >= 64u) best = tid * 4 + 3;
        if (best >= 0) atomicMax(&bstar, best);
    }
    __syncthreads();
    const unsigned kmin = (unsigned)(bstar < 0 ? 1 : bstar) << 5;

    // collect candidates >= kmin
#pragma unroll
    for (int p = 0; p < 4; ++p) {
        const unsigned ee[4] = {cv[p].x, cv[p].y, cv[p].z, cv[p].w};
#pragma unroll
        for (int e = 0; e < 4; ++e) {
            if (ee[e] && (ee[e] >> 16) >= kmin) {
                const int pos = atomicAdd(&cnt, 1);
                if (pos < NCAP) cent[pos] = ee[e];
            }
        }
    }
    __syncthreads();
    const int nc = min(cnt, NCAP);

    // approx-rank on packed u32 desc == (key desc, col asc); keep top NRE
    for (int p = tid; p < nc; p += 256) {
        const unsigned e = cent[p];
        int rr = 0;
        for (int j = 0; j < nc; ++j) rr += (cent[j] > e) ? 1 : 0;
        if (rr < NRE) r64i[rr] = 16383 - (int)(e & 0xFFFFu);
    }
    __syncthreads();

    // exact fp64 recompute against combined fp32 weights (single dot)
    const float* wsel = (q & 1) ? wrf : wcf;
    const int w = tid >> 6, lane = tid & 63;
    for (int c = w; c < NRE; c += 4) {
        const int idx = r64i[c];
        const float4* rp4 = (const float4*)(wsel + (size_t)idx * 512);
        const float4 r0 = rp4[lane * 2], r1 = rp4[lane * 2 + 1];
        const double* pv = prow + lane * 8;
        double aR = pv[0] * (double)r0.x + pv[1] * (double)r0.y + pv[2] * (double)r0.z + pv[3] * (double)r0.w
                  + pv[4] * (double)r1.x + pv[5] * (double)r1.y + pv[6] * (double)r1.z + pv[7] * (double)r1.w;
        for (int sh = 32; sh > 0; sh >>= 1) aR += __shfl_down(aR, sh);
        if (lane == 0) cval[c] = aR;
    }
    __syncthreads();

    // exact top-32 by (|v| desc, idx asc) -- matches lax.top_k tie semantics
    if (tid < NRE) {
        const double av = fabs(cval[tid]);
        const int mi = r64i[tid];
        int rr = 0;
        for (int j = 0; j < NRE; ++j) {
            const double aj = fabs(cval[j]);
            rr += (aj > av || (aj == av && r64i[j] < mi)) ? 1 : 0;
        }
        if (rr < 32) { selv[rr] = (float)cval[tid]; seli[rr] = mi; }
    }
    __syncthreads();
    if (tid < 32) {
        const size_t sb = ((size_t)q * 1024 + row) * 32 + tid;
        selvw[sb] = selv[tid];
        seliw[sb] = seli[tid];
    }

    // rep = sum_k v_k * atoms[idx_k]
    double a0 = 0, a1 = 0;
    for (int k = 0; k < 32; ++k) {
        const double v = (double)selv[k];
        const float* ar = atoms + (size_t)seli[k] * 512;
        a0 += v * (double)ar[tid];
        a1 += v * (double)ar[tid + 256];
    }
    float* rp = repw + ((size_t)q * 1024 + row) * 512;
    rp[tid] = (float)a0;
    rp[tid + 256] = (float)a1;
}

// ---------------- K6.5: zero the sparse output region (write peak) ---------
__global__ __launch_bounds__(256) void zero_kernel(float4* __restrict__ p, unsigned n4)
{
    const float4 z = {0.f, 0.f, 0.f, 0.f};
    unsigned i = blockIdx.x * 256u + threadIdx.x;
    const unsigned stride = gridDim.x * 256u;
    for (; i < n4; i += stride) p[i] = z;
}

// ---------------- K7: fused + heads + sparse scatter -----------------------
__global__ __launch_bounds__(256) void heads_kernel(
    const double* __restrict__ pw, const float* __restrict__ repw,
    const float* __restrict__ chw, const float* __restrict__ chb,
    const float* __restrict__ rhw, const float* __restrict__ rhb,
    const float* __restrict__ selvw, const int* __restrict__ seliw,
    float* __restrict__ out)
{
    const int row = blockIdx.x, s = blockIdx.y;
    const int tid = threadIdx.x;
    __shared__ double fused[512];

    // scatter this row's 64 selected values (runs after the zero fill)
    if (tid < 64) {
        const int qq = s * 2 + (tid >> 5), k = tid & 31;
        const size_t sb = ((size_t)qq * 1024 + row) * 32 + k;
        out[(size_t)OUT_SPARSE + (size_t)qq * SPARSE_PER + (size_t)row * 16384 + (size_t)seliw[sb]] = selvw[sb];
    }

    const double* pr = pw + ((size_t)s * 1024 + row) * 512;
    const float* rc = repw + ((size_t)(s * 2 + 0) * 1024 + row) * 512;
    const float* rr = repw + ((size_t)(s * 2 + 1) * 1024 + row) * 512;
    for (int d = tid; d < 512; d += 256)
        fused[d] = 0.2 * pr[d] + 0.9 * (double)rc[d] + 0.9 * (double)rr[d];
    __syncthreads();
    const int w = tid >> 6, lane = tid & 63;
    for (int o = w; o < 22; o += 4) {
        const float* hw2 = (o < 16) ? (chw + (size_t)o * 512) : (rhw + (size_t)(o - 16) * 512);
        double acc = 0;
#pragma unroll
        for (int j = 0; j < 8; ++j) acc += fused[lane + 64 * j] * (double)hw2[lane + 64 * j];
        for (int sh = 32; sh > 0; sh >>= 1) acc += __shfl_down(acc, sh);
        if (lane == 0) {
            if (o < 16) out[(s ? 22528 : 0) + row * 16 + o] = (float)(acc + (double)chb[o]);
            else        out[(s ? 38912 : 16384) + row * 6 + (o - 16)] = (float)(acc + (double)rhb[o - 16]);
        }
    }
}

// ---------------------------------------------------------------------------
extern "C" void kernel_launch(void* const* d_in, const int* in_sizes, int n_in,
                              void* d_out, int out_size, void* d_ws, size_t ws_size,
                              hipStream_t stream)
{
    const int*   ctok   = (const int*)d_in[0];
    const int*   ntok   = (const int*)d_in[1];
    const float* emb    = (const float*)d_in[2];
    const float* w1     = (const float*)d_in[3];
    const float* b1     = (const float*)d_in[4];
    const float* w2     = (const float*)d_in[5];
    const float* b2     = (const float*)d_in[6];
    const float* atoms  = (const float*)d_in[7];
    const float* router = (const float*)d_in[8];
    const float* cdelta = (const float*)d_in[9];
    const float* rdelta = (const float*)d_in[10];
    const float* chw    = (const float*)d_in[11];
    const float* chb    = (const float*)d_in[12];
    const float* rhw    = (const float*)d_in[13];
    const float* rhb    = (const float*)d_in[14];
    float* out = (float*)d_out;

    // staging inside the 256 MB sparse-output region (zeroed afterward)
    float*    wcf   = out + OUT_SPARSE;           // [16384*512] fp32 combined (concept)
    float*    wrf   = wcf + 8388608;              // [16384*512] fp32 combined (relation)
    unsigned* candg = (unsigned*)(wrf + 8388608); // [4*1024*128*32] packed candidates

    // workspace layout (66 MB, identical footprint to R2)
    double*    xw   = (double*)d_ws;              // [2*1024*512] fp64
    double*    hw   = xw + 1048576;               // [2*1024*512] fp64 (dead after enc_gemm#2)
    double*    pw   = hw + 1048576;               // [2*1024*512] fp64
    float*     repw = (float*)(pw + 1048576);     // [4*1024*512] fp32
    _Float16*  pf16 = (_Float16*)(repw + 2097152);// [2*1024*512] fp16
    _Float16*  wcw  = pf16 + 1048576;             // [16384*512] fp16
    _Float16*  wrw  = wcw + 8388608;              // [16384*512] fp16
    float*     selvw = (float*)hw;                // [4*1024*32] reuse dead hw buffer
    int*       seliw = (int*)(selvw + 131072);    // [4*1024*32]

    pool_kernel<<<dim3(1024, 2), 128, 0, stream>>>(ctok, ntok, emb, xw);
    enc_gemm<<<dim3(8, 32), 256, 0, stream>>>(xw, w1, b1, hw, (_Float16*)nullptr, 1);
    enc_gemm<<<dim3(8, 32), 256, 0, stream>>>(hw, w2, b2, pw, pf16, 0);
    combine_kernel<<<8192, 256, 0, stream>>>(router, cdelta, rdelta, wcw, wrw, wcf, wrf);
    approx_gemm<<<dim3(128, 8, 4), 256, 0, stream>>>(pf16, wcw, wrw, candg);
    select_kernel<<<dim3(1024, 4), 256, 0, stream>>>(pw, wcf, wrf, candg, atoms, selvw, seliw, repw);
    zero_kernel<<<2048, 256, 0, stream>>>((float4*)(out + OUT_SPARSE), (unsigned)SPARSE_PER);
    heads_kernel<<<dim3(1024, 2), 256, 0, stream>>>(pw, repw, chw, chb, rhw, rhb, selvw, seliw, out);
}

// Round 3
// 872.956 us; speedup vs baseline: 1.0042x; 1.0042x over previous
//
#include <hip/hip_runtime.h>

// ---------------------------------------------------------------------------
// SharedAtomModel: pooled-embedding encoder -> sparse dictionary top-k -> heads
//
// Sizes: B=1024 S=32 D=512 DICT=16384 TOPK=32
// Outputs (fp32, flat): [1024x16][1024x6][1024x16][1024x6][4 x 1024x16384]
//
// R5 changes vs R4 (counter-driven: approx_gemm 184us, 4.9e7 LDS conflicts,
// 31% occupancy, MfmaUtil 15.5%):
//  - approx_gemm rewritten: BK=64 (128 B LDS rows) with T2-style XOR swizzle.
//    global_load_lds writes linearly, so the SOURCE address is pre-swizzled
//    (rule 21) and fragment reads XOR the chunk index with (row&7) ->
//    2 lanes/bank-group = conflict-free b128 reads (was 8-way structural).
//  - Epilogue fully in registers: per-row sigma via __shfl_xor 16-lane
//    reduce + 128x2 LDS combine; candidates emitted straight from the f32
//    accumulators with identical fp16-bit keys (no 32 KB Cst staging, no
//    32-way-conflicted re-reads). LDS 48.5 -> ~33.5 KB.
//  - zero_kernel folded into heads_kernel: each block zeroes its own two
//    sparse rows, __syncthreads, then scatters its 64 selected values.
// ---------------------------------------------------------------------------

typedef _Float16 f16x8 __attribute__((ext_vector_type(8)));
typedef _Float16 f16x4 __attribute__((ext_vector_type(4)));
typedef float f32x4 __attribute__((ext_vector_type(4)));

#define OUT_SPARSE 45056
#define SPARSE_PER 16777216

#define ASYNC16(gp, lp) __builtin_amdgcn_global_load_lds(                      \
    (const __attribute__((address_space(1))) void*)(gp),                       \
    (__attribute__((address_space(3))) void*)(lp), 16, 0, 0)

// ---------------- K1: pooled mean embedding (fp64 accumulate) --------------
__global__ __launch_bounds__(128) void pool_kernel(
    const int* __restrict__ ct, const int* __restrict__ nt,
    const float* __restrict__ emb, double* __restrict__ xout)
{
    const int row = blockIdx.x, s = blockIdx.y;
    const int tid = threadIdx.x;
    __shared__ int tk[32];
    const int* t = (s ? nt : ct) + row * 32;
    if (tid < 32) tk[tid] = t[tid];
    __syncthreads();
    const int d = tid * 4;
    double a0 = 0, a1 = 0, a2 = 0, a3 = 0;
    for (int i = 0; i < 32; ++i) {
        const float4 v = *(const float4*)(emb + (size_t)tk[i] * 512 + d);
        a0 += (double)v.x; a1 += (double)v.y; a2 += (double)v.z; a3 += (double)v.w;
    }
    double* o = xout + ((size_t)s * 1024 + row) * 512 + d;
    o[0] = a0 * 0.03125; o[1] = a1 * 0.03125; o[2] = a2 * 0.03125; o[3] = a3 * 0.03125;
}

// ---------------- K2/K3: fp64 encoder GEMM: C = f(A @ W^T + b) -------------
__global__ __launch_bounds__(256) void enc_gemm(
    const double* __restrict__ A, const float* __restrict__ W,
    const float* __restrict__ bias, double* __restrict__ C,
    _Float16* __restrict__ C16, int act)
{
    __shared__ double Ask[16][68];
    __shared__ double Wsk[16][68];
    const int tid = threadIdx.x;
    const int m0 = blockIdx.y * 64, n0 = blockIdx.x * 64;
    const int ty = tid >> 4, tx = tid & 15;
    const int r = tid >> 2, c4 = (tid & 3) * 4;
    double acc[4][4] = {};
    for (int k0 = 0; k0 < 512; k0 += 16) {
        const double4 av = *(const double4*)(A + (size_t)(m0 + r) * 512 + k0 + c4);
        const float4  wv = *(const float4*) (W + (size_t)(n0 + r) * 512 + k0 + c4);
        __syncthreads();
        Ask[c4 + 0][r] = av.x; Ask[c4 + 1][r] = av.y; Ask[c4 + 2][r] = av.z; Ask[c4 + 3][r] = av.w;
        Wsk[c4 + 0][r] = (double)wv.x; Wsk[c4 + 1][r] = (double)wv.y;
        Wsk[c4 + 2][r] = (double)wv.z; Wsk[c4 + 3][r] = (double)wv.w;
        __syncthreads();
#pragma unroll
        for (int k = 0; k < 16; ++k) {
            const double4 a = *(const double4*)&Ask[k][ty * 4];
            const double4 b = *(const double4*)&Wsk[k][tx * 4];
            const double aa[4] = {a.x, a.y, a.z, a.w};
            const double bb[4] = {b.x, b.y, b.z, b.w};
#pragma unroll
            for (int i = 0; i < 4; ++i)
#pragma unroll
                for (int j = 0; j < 4; ++j) acc[i][j] += aa[i] * bb[j];
        }
    }
#pragma unroll
    for (int i = 0; i < 4; ++i) {
        const int row = m0 + ty * 4 + i;
#pragma unroll
        for (int j = 0; j < 4; ++j) {
            const int col = n0 + tx * 4 + j;
            double v = acc[i][j] + (double)bias[col];
            if (act) v = v / (1.0 + exp(-v));   // silu
            C[(size_t)row * 512 + col] = v;
            if (C16) C16[(size_t)row * 512 + col] = (_Float16)v;
        }
    }
}

// ---------------- K4: combined fp16 + fp32 weights -------------------------
__global__ __launch_bounds__(256) void combine_kernel(
    const float* __restrict__ router, const float* __restrict__ cd,
    const float* __restrict__ rd, _Float16* __restrict__ wc,
    _Float16* __restrict__ wr, float* __restrict__ wcf,
    float* __restrict__ wrf)
{
    const size_t i = ((size_t)blockIdx.x * 256 + threadIdx.x) * 4;
    if (i >= (size_t)16384 * 512) return;
    const float4 r = *(const float4*)(router + i);
    const float4 c = *(const float4*)(cd + i);
    const float4 d = *(const float4*)(rd + i);
    const float4 fc = { r.x + 0.3f * c.x, r.y + 0.3f * c.y, r.z + 0.3f * c.z, r.w + 0.3f * c.w };
    const float4 fr = { r.x + 0.3f * d.x, r.y + 0.3f * d.y, r.z + 0.3f * d.z, r.w + 0.3f * d.w };
    f16x4 hc = { (_Float16)fc.x, (_Float16)fc.y, (_Float16)fc.z, (_Float16)fc.w };
    f16x4 hr = { (_Float16)fr.x, (_Float16)fr.y, (_Float16)fr.z, (_Float16)fr.w };
    *(f16x4*)(wc + i) = hc;
    *(f16x4*)(wr + i) = hr;
    *(float4*)(wcf + i) = fc;
    *(float4*)(wrf + i) = fr;
}

// ---------------- K5: fp16 MFMA approx GEMM + in-register emission ---------
// 128x128 tile, BK=64. LDS rows are 128 B; LDS[r][c] holds global chunk
// c^(r&7) (source pre-swizzled since global_load_lds writes linearly);
// fragment reads XOR the chunk index with (r&7) -> 2 lanes/bank-group.
// Epilogue: per-row sigma from f32 accs (shfl reduce), candidates
// (key15<<16 | 16383-col) for |v| >= 2*sigma_tile, 32 slots/row, zero-pad.
__global__ __launch_bounds__(256) void approx_gemm(
    const _Float16* __restrict__ P, const _Float16* __restrict__ Wc,
    const _Float16* __restrict__ Wr, unsigned* __restrict__ candg)
{
    __shared__ _Float16 As[8192];           // [128][64] fp16 (128 B rows)
    __shared__ _Float16 Bs[8192];
    __shared__ float    ssp[128][2];
    __shared__ unsigned cutk_s[128];
    __shared__ unsigned ecnt[128];

    const int tid = threadIdx.x;
    const int q = blockIdx.z;
    const int n0 = blockIdx.x * 128, m0 = blockIdx.y * 128;
    const _Float16* Agbl = P + (size_t)(q >> 1) * 524288;
    const _Float16* Bgbl = (q & 1) ? Wr : Wc;

    const int lane = tid & 63, w = tid >> 6;
    const int wm = w & 1, wn = w >> 1;
    const int lr = lane & 15, lk = lane >> 4;
    const int xr = lr & 7;

    // staging: issue i covers row-group G = i*4+w (8 rows x 128 B = 1 KB/wave)
    const int srow = lane >> 3;             // row within group (== r&7)
    const int cg = (lane & 7) ^ srow;       // pre-swizzled source chunk
    const _Float16* ag[4];
    const _Float16* bg[4];
    _Float16* al[4];
    _Float16* bl[4];
#pragma unroll
    for (int i = 0; i < 4; ++i) {
        const int G = i * 4 + w;
        const int rr0 = G * 8 + srow;
        ag[i] = Agbl + (size_t)(m0 + rr0) * 512 + cg * 8;
        bg[i] = Bgbl + (size_t)(n0 + rr0) * 512 + cg * 8;
        al[i] = As + G * 512;               // wave-uniform; HW adds lane*16B
        bl[i] = Bs + G * 512;
    }

    const f32x4 zero = {0.f, 0.f, 0.f, 0.f};
    f32x4 acc[4][4];
#pragma unroll
    for (int i = 0; i < 4; ++i)
#pragma unroll
        for (int j = 0; j < 4; ++j) acc[i][j] = zero;

    for (int kt = 0; kt < 8; ++kt) {
        const int k0 = kt * 64;
        __syncthreads();                 // prev iter's ds_reads done
#pragma unroll
        for (int i = 0; i < 4; ++i) ASYNC16(ag[i] + k0, al[i]);
#pragma unroll
        for (int i = 0; i < 4; ++i) ASYNC16(bg[i] + k0, bl[i]);
        __syncthreads();                 // implies vmcnt(0): tiles ready
#pragma unroll
        for (int kk = 0; kk < 2; ++kk) {
            f16x8 af[4], bf[4];
#pragma unroll
            for (int i = 0; i < 4; ++i)
                af[i] = *(const f16x8*)(As + (wm * 64 + i * 16 + lr) * 64 + (((kk << 2) | lk) ^ xr) * 8);
#pragma unroll
            for (int j = 0; j < 4; ++j)
                bf[j] = *(const f16x8*)(Bs + (wn * 64 + j * 16 + lr) * 64 + (((kk << 2) | lk) ^ xr) * 8);
#pragma unroll
            for (int i = 0; i < 4; ++i)
#pragma unroll
                for (int j = 0; j < 4; ++j)
                    acc[i][j] = __builtin_amdgcn_mfma_f32_16x16x32_f16(af[i], bf[j], acc[i][j], 0, 0, 0);
        }
    }

    // ---- per-row sigma from registers ----
    // C/D layout: col = wn*64 + j*16 + (lane&15), row = wm*64 + i*16 + (lane>>4)*4 + rr
    if (tid < 128) ecnt[tid] = 0;
#pragma unroll
    for (int i = 0; i < 4; ++i)
#pragma unroll
        for (int rr = 0; rr < 4; ++rr) {
            float s = 0.f;
#pragma unroll
            for (int j = 0; j < 4; ++j) { const float v = acc[i][j][rr]; s = fmaf(v, v, s); }
            s += __shfl_xor(s, 1); s += __shfl_xor(s, 2);
            s += __shfl_xor(s, 4); s += __shfl_xor(s, 8);
            if (lr == 0) ssp[wm * 64 + i * 16 + lk * 4 + rr][wn] = s;
        }
    __syncthreads();                        // ssp visible; all As reads done
    if (tid < 128) {
        const float sig2 = (ssp[tid][0] + ssp[tid][1]) * (1.f / 128.f);
        const _Float16 hc = (_Float16)(2.0f * sqrtf(sig2));
        cutk_s[tid] = (unsigned)__builtin_bit_cast(unsigned short, hc) & 0x7FFFu;
    }
    __syncthreads();

    // ---- emission straight from registers ----
    unsigned* emit = (unsigned*)As;         // 128 rows x 32 slots = 16 KB
#pragma unroll
    for (int i = 0; i < 4; ++i)
#pragma unroll
        for (int rr = 0; rr < 4; ++rr) {
            const int row = wm * 64 + i * 16 + lk * 4 + rr;
            const unsigned ck = cutk_s[row];
#pragma unroll
            for (int j = 0; j < 4; ++j) {
                const float v = acc[i][j][rr];
                const _Float16 hv = (_Float16)v;
                const unsigned key = (unsigned)__builtin_bit_cast(unsigned short, hv) & 0x7FFFu;
                if (key >= ck && key) {
                    const unsigned pos = atomicAdd(&ecnt[row], 1u);
                    const int col = n0 + wn * 64 + j * 16 + lr;
                    if (pos < 32u) emit[row * 32 + pos] = (key << 16) | (unsigned)(16383 - col);
                }
            }
        }
    __syncthreads();
    // zero-pad own half and store 64 B per thread
    {
        const int r2 = tid >> 1, h2 = tid & 1;
        const unsigned c = min(ecnt[r2], 32u);
#pragma unroll
        for (int s2 = 0; s2 < 16; ++s2) {
            const unsigned sl = (unsigned)(h2 * 16 + s2);
            if (sl >= c) emit[r2 * 32 + sl] = 0u;
        }
        unsigned* eg = candg + (((size_t)q * 1024 + m0 + r2) * 128 + blockIdx.x) * 32;
        const uint4* e4 = (const uint4*)(emit + r2 * 32 + h2 * 16);
        uint4* g4 = (uint4*)(eg + h2 * 16);
        g4[0] = e4[0]; g4[1] = e4[1]; g4[2] = e4[2]; g4[3] = e4[3];
    }
}

// ---------------- K6: select + exact recompute (compact output) ------------
__global__ __launch_bounds__(256) void select_kernel(
    const double* __restrict__ pw, const float* __restrict__ wcf,
    const float* __restrict__ wrf, const unsigned* __restrict__ candg,
    const float* __restrict__ atoms, float* __restrict__ selvw,
    int* __restrict__ seliw, float* __restrict__ repw)
{
    constexpr int NCAP = 160, NRE = 64;
    const int row = blockIdx.x, q = blockIdx.y;
    const int pset = q >> 1;
    const int tid = threadIdx.x;

    __shared__ unsigned hist[1024];
    __shared__ unsigned pscan[256];
    __shared__ double prow[512];
    __shared__ unsigned cent[NCAP];
    __shared__ int r64i[NRE];
    __shared__ double cval[NRE];
    __shared__ float selv[32];
    __shared__ int seli[32];
    __shared__ int cnt, bstar;

    const double* prg = pw + ((size_t)pset * 1024 + row) * 512;
    const unsigned* crow = candg + ((size_t)q * 1024 + row) * 4096;

    for (int b = tid; b < 1024; b += 256) hist[b] = 0;
    if (tid == 0) { cnt = 0; bstar = -1; }
    if (tid < NRE) r64i[tid] = 0;
    prow[tid] = prg[tid];
    prow[tid + 256] = prg[tid + 256];

    uint4 cv[4];
#pragma unroll
    for (int p = 0; p < 4; ++p) cv[p] = ((const uint4*)crow)[p * 256 + tid];
    __syncthreads();

    // histogram of key>>5 (1024 bins); sentinel 0 entries skipped
#pragma unroll
    for (int p = 0; p < 4; ++p) {
        const unsigned ee[4] = {cv[p].x, cv[p].y, cv[p].z, cv[p].w};
#pragma unroll
        for (int e = 0; e < 4; ++e)
            if (ee[e]) atomicAdd(&hist[ee[e] >> 21], 1u);
    }
    __syncthreads();

    // suffix-scan from the top to find key threshold with >=64 above
    const unsigned h0 = hist[tid * 4], h1 = hist[tid * 4 + 1];
    const unsigned h2 = hist[tid * 4 + 2], h3 = hist[tid * 4 + 3];
    const unsigned l3 = h3, l2 = h2 + l3, l1 = h1 + l2, l0 = h0 + l1;
    pscan[tid] = l0;
    __syncthreads();
    for (int s = 1; s < 256; s <<= 1) {
        const unsigned v = (tid + s < 256) ? pscan[tid + s] : 0u;
        __syncthreads();
        pscan[tid] += v;
        __syncthreads();
    }
    {
        const unsigned above = (tid < 255) ? pscan[tid + 1] : 0u;
        int best = -1;
        if (l0 + above >= 64u) best = tid * 4;
        if (l1 + above >= 64u) best = tid * 4 + 1;
        if (l2 + above >= 64u) best = tid * 4 + 2;
        if (l3 + above >= 64u) best = tid * 4 + 3;
        if (best >= 0) atomicMax(&bstar, best);
    }
    __syncthreads();
    const unsigned kmin = (unsigned)(bstar < 0 ? 1 : bstar) << 5;

    // collect candidates >= kmin
#pragma unroll
    for (int p = 0; p < 4; ++p) {
        const unsigned ee[4] = {cv[p].x, cv[p].y, cv[p].z, cv[p].w};
#pragma unroll
        for (int e = 0; e < 4; ++e) {
            if (ee[e] && (ee[e] >> 16) >= kmin) {
                const int pos = atomicAdd(&cnt, 1);
                if (pos < NCAP) cent[pos] = ee[e];
            }
        }
    }
    __syncthreads();
    const int nc = min(cnt, NCAP);

    // approx-rank on packed u32 desc == (key desc, col asc); keep top NRE
    for (int p = tid; p < nc; p += 256) {
        const unsigned e = cent[p];
        int rr = 0;
        for (int j = 0; j < nc; ++j) rr += (cent[j] > e) ? 1 : 0;
        if (rr < NRE) r64i[rr] = 16383 - (int)(e & 0xFFFFu);
    }
    __syncthreads();

    // exact fp64 recompute against combined fp32 weights (single dot)
    const float* wsel = (q & 1) ? wrf : wcf;
    const int w = tid >> 6, lane = tid & 63;
    for (int c = w; c < NRE; c += 4) {
        const int idx = r64i[c];
        const float4* rp4 = (const float4*)(wsel + (size_t)idx * 512);
        const float4 r0 = rp4[lane * 2], r1 = rp4[lane * 2 + 1];
        const double* pv = prow + lane * 8;
        double aR = pv[0] * (double)r0.x + pv[1] * (double)r0.y + pv[2] * (double)r0.z + pv[3] * (double)r0.w
                  + pv[4] * (double)r1.x + pv[5] * (double)r1.y + pv[6] * (double)r1.z + pv[7] * (double)r1.w;
        for (int sh = 32; sh > 0; sh >>= 1) aR += __shfl_down(aR, sh);
        if (lane == 0) cval[c] = aR;
    }
    __syncthreads();

    // exact top-32 by (|v| desc, idx asc) -- matches lax.top_k tie semantics
    if (tid < NRE) {
        const double av = fabs(cval[tid]);
        const int mi = r64i[tid];
        int rr = 0;
        for (int j = 0; j < NRE; ++j) {
            const double aj = fabs(cval[j]);
            rr += (aj > av || (aj == av && r64i[j] < mi)) ? 1 : 0;
        }
        if (rr < 32) { selv[rr] = (float)cval[tid]; seli[rr] = mi; }
    }
    __syncthreads();
    if (tid < 32) {
        const size_t sb = ((size_t)q * 1024 + row) * 32 + tid;
        selvw[sb] = selv[tid];
        seliw[sb] = seli[tid];
    }

    // rep = sum_k v_k * atoms[idx_k]
    double a0 = 0, a1 = 0;
    for (int k = 0; k < 32; ++k) {
        const double v = (double)selv[k];
        const float* ar = atoms + (size_t)seli[k] * 512;
        a0 += v * (double)ar[tid];
        a1 += v * (double)ar[tid + 256];
    }
    float* rp = repw + ((size_t)q * 1024 + row) * 512;
    rp[tid] = (float)a0;
    rp[tid + 256] = (float)a1;
}

// ---------------- K7: zero own sparse rows + fused + heads + scatter -------
__global__ __launch_bounds__(256) void heads_kernel(
    const double* __restrict__ pw, const float* __restrict__ repw,
    const float* __restrict__ chw, const float* __restrict__ chb,
    const float* __restrict__ rhw, const float* __restrict__ rhb,
    const float* __restrict__ selvw, const int* __restrict__ seliw,
    float* __restrict__ out)
{
    const int row = blockIdx.x, s = blockIdx.y;
    const int tid = threadIdx.x;
    __shared__ double fused[512];

    // zero this block's two sparse rows (q = 2s, 2s+1)
    float4* z0 = (float4*)(out + (size_t)OUT_SPARSE + (size_t)(2 * s + 0) * SPARSE_PER + (size_t)row * 16384);
    float4* z1 = (float4*)(out + (size_t)OUT_SPARSE + (size_t)(2 * s + 1) * SPARSE_PER + (size_t)row * 16384);
    const float4 z = {0.f, 0.f, 0.f, 0.f};
#pragma unroll
    for (int i = 0; i < 16; ++i) { z0[i * 256 + tid] = z; z1[i * 256 + tid] = z; }

    const double* pr = pw + ((size_t)s * 1024 + row) * 512;
    const float* rc = repw + ((size_t)(s * 2 + 0) * 1024 + row) * 512;
    const float* rr = repw + ((size_t)(s * 2 + 1) * 1024 + row) * 512;
    for (int d = tid; d < 512; d += 256)
        fused[d] = 0.2 * pr[d] + 0.9 * (double)rc[d] + 0.9 * (double)rr[d];
    __syncthreads();   // zero writes done block-wide; fused visible

    // scatter this row's 64 selected values over the zeroed rows
    if (tid < 64) {
        const int qq = s * 2 + (tid >> 5), k = tid & 31;
        const size_t sb = ((size_t)qq * 1024 + row) * 32 + k;
        out[(size_t)OUT_SPARSE + (size_t)qq * SPARSE_PER + (size_t)row * 16384 + (size_t)seliw[sb]] = selvw[sb];
    }

    const int w = tid >> 6, lane = tid & 63;
    for (int o = w; o < 22; o += 4) {
        const float* hw2 = (o < 16) ? (chw + (size_t)o * 512) : (rhw + (size_t)(o - 16) * 512);
        double acc = 0;
#pragma unroll
        for (int j = 0; j < 8; ++j) acc += fused[lane + 64 * j] * (double)hw2[lane + 64 * j];
        for (int sh = 32; sh > 0; sh >>= 1) acc += __shfl_down(acc, sh);
        if (lane == 0) {
            if (o < 16) out[(s ? 22528 : 0) + row * 16 + o] = (float)(acc + (double)chb[o]);
            else        out[(s ? 38912 : 16384) + row * 6 + (o - 16)] = (float)(acc + (double)rhb[o - 16]);
        }
    }
}

// ---------------------------------------------------------------------------
extern "C" void kernel_launch(void* const* d_in, const int* in_sizes, int n_in,
                              void* d_out, int out_size, void* d_ws, size_t ws_size,
                              hipStream_t stream)
{
    const int*   ctok   = (const int*)d_in[0];
    const int*   ntok   = (const int*)d_in[1];
    const float* emb    = (const float*)d_in[2];
    const float* w1     = (const float*)d_in[3];
    const float* b1     = (const float*)d_in[4];
    const float* w2     = (const float*)d_in[5];
    const float* b2     = (const float*)d_in[6];
    const float* atoms  = (const float*)d_in[7];
    const float* router = (const float*)d_in[8];
    const float* cdelta = (const float*)d_in[9];
    const float* rdelta = (const float*)d_in[10];
    const float* chw    = (const float*)d_in[11];
    const float* chb    = (const float*)d_in[12];
    const float* rhw    = (const float*)d_in[13];
    const float* rhb    = (const float*)d_in[14];
    float* out = (float*)d_out;

    // staging inside the 256 MB sparse-output region (zeroed by heads_kernel)
    float*    wcf   = out + OUT_SPARSE;           // [16384*512] fp32 combined (concept)
    float*    wrf   = wcf + 8388608;              // [16384*512] fp32 combined (relation)
    unsigned* candg = (unsigned*)(wrf + 8388608); // [4*1024*128*32] packed candidates

    // workspace layout (66 MB, identical footprint to R2)
    double*    xw   = (double*)d_ws;              // [2*1024*512] fp64
    double*    hw   = xw + 1048576;               // [2*1024*512] fp64 (dead after enc_gemm#2)
    double*    pw   = hw + 1048576;               // [2*1024*512] fp64
    float*     repw = (float*)(pw + 1048576);     // [4*1024*512] fp32
    _Float16*  pf16 = (_Float16*)(repw + 2097152);// [2*1024*512] fp16
    _Float16*  wcw  = pf16 + 1048576;             // [16384*512] fp16
    _Float16*  wrw  = wcw + 8388608;              // [16384*512] fp16
    float*     selvw = (float*)hw;                // [4*1024*32] reuse dead hw buffer
    int*       seliw = (int*)(selvw + 131072);    // [4*1024*32]

    pool_kernel<<<dim3(1024, 2), 128, 0, stream>>>(ctok, ntok, emb, xw);
    enc_gemm<<<dim3(8, 32), 256, 0, stream>>>(xw, w1, b1, hw, (_Float16*)nullptr, 1);
    enc_gemm<<<dim3(8, 32), 256, 0, stream>>>(hw, w2, b2, pw, pf16, 0);
    combine_kernel<<<8192, 256, 0, stream>>>(router, cdelta, rdelta, wcw, wrw, wcf, wrf);
    approx_gemm<<<dim3(128, 8, 4), 256, 0, stream>>>(pf16, wcw, wrw, candg);
    select_kernel<<<dim3(1024, 4), 256, 0, stream>>>(pw, wcf, wrf, candg, atoms, selvw, seliw, repw);
    heads_kernel<<<dim3(1024, 2), 256, 0, stream>>>(pw, repw, chw, chb, rhw, rhb, selvw, seliw, out);
}

// Round 4
// 867.882 us; speedup vs baseline: 1.0101x; 1.0058x over previous
//
#include <hip/hip_runtime.h>

// ---------------------------------------------------------------------------
// SharedAtomModel: pooled-embedding encoder -> sparse dictionary top-k -> heads
//
// Sizes: B=1024 S=32 D=512 DICT=16384 TOPK=32
// Outputs (fp32, flat): [1024x16][1024x6][1024x16][1024x6][4 x 1024x16384]
//
// R6 changes vs R5 (post-mortem: conflict fix worked, 5x fewer conflicts,
// but dur flat at 187us -> bottleneck is latency serialization: each K-step
// exposed full load latency at ~1.8 blocks/CU TLP):
//  - approx_gemm: double-buffered LDS + 2-phase pipeline (T3 minimum form).
//    Issue tile t+1's global_load_lds BEFORE computing tile t; ONE barrier
//    per K-step. The compiler's vmcnt(0)-before-s_barrier now waits on loads
//    that had the whole compute phase (~350 cyc) in flight -> drain ~free.
//    Barriers per block 16 -> 8. LDS 34 -> 66 KB (2 blocks/CU; in-block
//    overlap replaces TLP).
//  - Everything else unchanged (single-variable round).
// ---------------------------------------------------------------------------

typedef _Float16 f16x8 __attribute__((ext_vector_type(8)));
typedef _Float16 f16x4 __attribute__((ext_vector_type(4)));
typedef float f32x4 __attribute__((ext_vector_type(4)));

#define OUT_SPARSE 45056
#define SPARSE_PER 16777216

#define ASYNC16(gp, lp) __builtin_amdgcn_global_load_lds(                      \
    (const __attribute__((address_space(1))) void*)(gp),                       \
    (__attribute__((address_space(3))) void*)(lp), 16, 0, 0)

// ---------------- K1: pooled mean embedding (fp64 accumulate) --------------
__global__ __launch_bounds__(128) void pool_kernel(
    const int* __restrict__ ct, const int* __restrict__ nt,
    const float* __restrict__ emb, double* __restrict__ xout)
{
    const int row = blockIdx.x, s = blockIdx.y;
    const int tid = threadIdx.x;
    __shared__ int tk[32];
    const int* t = (s ? nt : ct) + row * 32;
    if (tid < 32) tk[tid] = t[tid];
    __syncthreads();
    const int d = tid * 4;
    double a0 = 0, a1 = 0, a2 = 0, a3 = 0;
    for (int i = 0; i < 32; ++i) {
        const float4 v = *(const float4*)(emb + (size_t)tk[i] * 512 + d);
        a0 += (double)v.x; a1 += (double)v.y; a2 += (double)v.z; a3 += (double)v.w;
    }
    double* o = xout + ((size_t)s * 1024 + row) * 512 + d;
    o[0] = a0 * 0.03125; o[1] = a1 * 0.03125; o[2] = a2 * 0.03125; o[3] = a3 * 0.03125;
}

// ---------------- K2/K3: fp64 encoder GEMM: C = f(A @ W^T + b) -------------
__global__ __launch_bounds__(256) void enc_gemm(
    const double* __restrict__ A, const float* __restrict__ W,
    const float* __restrict__ bias, double* __restrict__ C,
    _Float16* __restrict__ C16, int act)
{
    __shared__ double Ask[16][68];
    __shared__ double Wsk[16][68];
    const int tid = threadIdx.x;
    const int m0 = blockIdx.y * 64, n0 = blockIdx.x * 64;
    const int ty = tid >> 4, tx = tid & 15;
    const int r = tid >> 2, c4 = (tid & 3) * 4;
    double acc[4][4] = {};
    for (int k0 = 0; k0 < 512; k0 += 16) {
        const double4 av = *(const double4*)(A + (size_t)(m0 + r) * 512 + k0 + c4);
        const float4  wv = *(const float4*) (W + (size_t)(n0 + r) * 512 + k0 + c4);
        __syncthreads();
        Ask[c4 + 0][r] = av.x; Ask[c4 + 1][r] = av.y; Ask[c4 + 2][r] = av.z; Ask[c4 + 3][r] = av.w;
        Wsk[c4 + 0][r] = (double)wv.x; Wsk[c4 + 1][r] = (double)wv.y;
        Wsk[c4 + 2][r] = (double)wv.z; Wsk[c4 + 3][r] = (double)wv.w;
        __syncthreads();
#pragma unroll
        for (int k = 0; k < 16; ++k) {
            const double4 a = *(const double4*)&Ask[k][ty * 4];
            const double4 b = *(const double4*)&Wsk[k][tx * 4];
            const double aa[4] = {a.x, a.y, a.z, a.w};
            const double bb[4] = {b.x, b.y, b.z, b.w};
#pragma unroll
            for (int i = 0; i < 4; ++i)
#pragma unroll
                for (int j = 0; j < 4; ++j) acc[i][j] += aa[i] * bb[j];
        }
    }
#pragma unroll
    for (int i = 0; i < 4; ++i) {
        const int row = m0 + ty * 4 + i;
#pragma unroll
        for (int j = 0; j < 4; ++j) {
            const int col = n0 + tx * 4 + j;
            double v = acc[i][j] + (double)bias[col];
            if (act) v = v / (1.0 + exp(-v));   // silu
            C[(size_t)row * 512 + col] = v;
            if (C16) C16[(size_t)row * 512 + col] = (_Float16)v;
        }
    }
}

// ---------------- K4: combined fp16 + fp32 weights -------------------------
__global__ __launch_bounds__(256) void combine_kernel(
    const float* __restrict__ router, const float* __restrict__ cd,
    const float* __restrict__ rd, _Float16* __restrict__ wc,
    _Float16* __restrict__ wr, float* __restrict__ wcf,
    float* __restrict__ wrf)
{
    const size_t i = ((size_t)blockIdx.x * 256 + threadIdx.x) * 4;
    if (i >= (size_t)16384 * 512) return;
    const float4 r = *(const float4*)(router + i);
    const float4 c = *(const float4*)(cd + i);
    const float4 d = *(const float4*)(rd + i);
    const float4 fc = { r.x + 0.3f * c.x, r.y + 0.3f * c.y, r.z + 0.3f * c.z, r.w + 0.3f * c.w };
    const float4 fr = { r.x + 0.3f * d.x, r.y + 0.3f * d.y, r.z + 0.3f * d.z, r.w + 0.3f * d.w };
    f16x4 hc = { (_Float16)fc.x, (_Float16)fc.y, (_Float16)fc.z, (_Float16)fc.w };
    f16x4 hr = { (_Float16)fr.x, (_Float16)fr.y, (_Float16)fr.z, (_Float16)fr.w };
    *(f16x4*)(wc + i) = hc;
    *(f16x4*)(wr + i) = hr;
    *(float4*)(wcf + i) = fc;
    *(float4*)(wrf + i) = fr;
}

// ---------------- K5: fp16 MFMA approx GEMM, 2-phase pipelined -------------
// 128x128 tile, BK=64, double-buffered LDS. LDS[r][c] holds global chunk
// c^(r&7) (source pre-swizzled; global_load_lds writes linearly); fragment
// reads XOR the chunk index with (r&7). Per K-step: stage t+1 into buf^1,
// compute buf, ONE barrier (its vmcnt(0) waits on loads that flew during
// compute). Epilogue: in-register sigma + candidate emission.
__global__ __launch_bounds__(256) void approx_gemm(
    const _Float16* __restrict__ P, const _Float16* __restrict__ Wc,
    const _Float16* __restrict__ Wr, unsigned* __restrict__ candg)
{
    __shared__ _Float16 As[2][8192];        // [buf][128 rows x 64 halves]
    __shared__ _Float16 Bs[2][8192];
    __shared__ float    ssp[128][2];
    __shared__ unsigned cutk_s[128];
    __shared__ unsigned ecnt[128];

    const int tid = threadIdx.x;
    const int q = blockIdx.z;
    const int n0 = blockIdx.x * 128, m0 = blockIdx.y * 128;
    const _Float16* Agbl = P + (size_t)(q >> 1) * 524288;
    const _Float16* Bgbl = (q & 1) ? Wr : Wc;

    const int lane = tid & 63, w = tid >> 6;
    const int wm = w & 1, wn = w >> 1;
    const int lr = lane & 15, lk = lane >> 4;
    const int xr = lr & 7;

    // staging: issue i covers row-group G = i*4+w (8 rows x 128 B = 1 KB/wave)
    const int srow = lane >> 3;             // row within group (== r&7)
    const int cg = (lane & 7) ^ srow;       // pre-swizzled source chunk
    const _Float16* ag[4];
    const _Float16* bg[4];
    int gofs[4];
#pragma unroll
    for (int i = 0; i < 4; ++i) {
        const int G = i * 4 + w;
        const int rr0 = G * 8 + srow;
        ag[i] = Agbl + (size_t)(m0 + rr0) * 512 + cg * 8;
        bg[i] = Bgbl + (size_t)(n0 + rr0) * 512 + cg * 8;
        gofs[i] = G * 512;                  // wave-uniform; HW adds lane*16B
    }

    const f32x4 zero = {0.f, 0.f, 0.f, 0.f};
    f32x4 acc[4][4];
#pragma unroll
    for (int i = 0; i < 4; ++i)
#pragma unroll
        for (int j = 0; j < 4; ++j) acc[i][j] = zero;

    // prologue: stage tile 0 into buf 0
#pragma unroll
    for (int i = 0; i < 4; ++i) { ASYNC16(ag[i], &As[0][gofs[i]]); ASYNC16(bg[i], &Bs[0][gofs[i]]); }
    __syncthreads();                        // vmcnt(0) drain: tile 0 ready

    int cur = 0;
    for (int kt = 0; kt < 8; ++kt) {
        const int nxt = cur ^ 1;
        if (kt < 7) {                       // issue next tile FIRST (in flight
            const int k0n = (kt + 1) * 64;  // during this tile's compute)
#pragma unroll
            for (int i = 0; i < 4; ++i) {
                ASYNC16(ag[i] + k0n, &As[nxt][gofs[i]]);
                ASYNC16(bg[i] + k0n, &Bs[nxt][gofs[i]]);
            }
        }
#pragma unroll
        for (int kk = 0; kk < 2; ++kk) {
            f16x8 af[4], bf[4];
#pragma unroll
            for (int i = 0; i < 4; ++i)
                af[i] = *(const f16x8*)(&As[cur][0] + (wm * 64 + i * 16 + lr) * 64 + (((kk << 2) | lk) ^ xr) * 8);
#pragma unroll
            for (int j = 0; j < 4; ++j)
                bf[j] = *(const f16x8*)(&Bs[cur][0] + (wn * 64 + j * 16 + lr) * 64 + (((kk << 2) | lk) ^ xr) * 8);
#pragma unroll
            for (int i = 0; i < 4; ++i)
#pragma unroll
                for (int j = 0; j < 4; ++j)
                    acc[i][j] = __builtin_amdgcn_mfma_f32_16x16x32_f16(af[i], bf[j], acc[i][j], 0, 0, 0);
        }
        __syncthreads();   // all reads of buf[cur] done; next tile landed
        cur = nxt;
    }

    // ---- per-row sigma from registers ----
    // C/D layout: col = wn*64 + j*16 + (lane&15), row = wm*64 + i*16 + (lane>>4)*4 + rr
    if (tid < 128) ecnt[tid] = 0;
#pragma unroll
    for (int i = 0; i < 4; ++i)
#pragma unroll
        for (int rr = 0; rr < 4; ++rr) {
            float s = 0.f;
#pragma unroll
            for (int j = 0; j < 4; ++j) { const float v = acc[i][j][rr]; s = fmaf(v, v, s); }
            s += __shfl_xor(s, 1); s += __shfl_xor(s, 2);
            s += __shfl_xor(s, 4); s += __shfl_xor(s, 8);
            if (lr == 0) ssp[wm * 64 + i * 16 + lk * 4 + rr][wn] = s;
        }
    __syncthreads();                        // ssp visible; LDS reads all done
    if (tid < 128) {
        const float sig2 = (ssp[tid][0] + ssp[tid][1]) * (1.f / 128.f);
        const _Float16 hc = (_Float16)(2.0f * sqrtf(sig2));
        cutk_s[tid] = (unsigned)__builtin_bit_cast(unsigned short, hc) & 0x7FFFu;
    }
    __syncthreads();

    // ---- emission straight from registers ----
    unsigned* emit = (unsigned*)&As[0][0];  // 128 rows x 32 slots = 16 KB
#pragma unroll
    for (int i = 0; i < 4; ++i)
#pragma unroll
        for (int rr = 0; rr < 4; ++rr) {
            const int row = wm * 64 + i * 16 + lk * 4 + rr;
            const unsigned ck = cutk_s[row];
#pragma unroll
            for (int j = 0; j < 4; ++j) {
                const float v = acc[i][j][rr];
                const _Float16 hv = (_Float16)v;
                const unsigned key = (unsigned)__builtin_bit_cast(unsigned short, hv) & 0x7FFFu;
                if (key >= ck && key) {
                    const unsigned pos = atomicAdd(&ecnt[row], 1u);
                    const int col = n0 + wn * 64 + j * 16 + lr;
                    if (pos < 32u) emit[row * 32 + pos] = (key << 16) | (unsigned)(16383 - col);
                }
            }
        }
    __syncthreads();
    // zero-pad own half and store 64 B per thread
    {
        const int r2 = tid >> 1, h2 = tid & 1;
        const unsigned c = min(ecnt[r2], 32u);
#pragma unroll
        for (int s2 = 0; s2 < 16; ++s2) {
            const unsigned sl = (unsigned)(h2 * 16 + s2);
            if (sl >= c) emit[r2 * 32 + sl] = 0u;
        }
        unsigned* eg = candg + (((size_t)q * 1024 + m0 + r2) * 128 + blockIdx.x) * 32;
        const uint4* e4 = (const uint4*)(emit + r2 * 32 + h2 * 16);
        uint4* g4 = (uint4*)(eg + h2 * 16);
        g4[0] = e4[0]; g4[1] = e4[1]; g4[2] = e4[2]; g4[3] = e4[3];
    }
}

// ---------------- K6: select + exact recompute (compact output) ------------
__global__ __launch_bounds__(256) void select_kernel(
    const double* __restrict__ pw, const float* __restrict__ wcf,
    const float* __restrict__ wrf, const unsigned* __restrict__ candg,
    const float* __restrict__ atoms, float* __restrict__ selvw,
    int* __restrict__ seliw, float* __restrict__ repw)
{
    constexpr int NCAP = 160, NRE = 64;
    const int row = blockIdx.x, q = blockIdx.y;
    const int pset = q >> 1;
    const int tid = threadIdx.x;

    __shared__ unsigned hist[1024];
    __shared__ unsigned pscan[256];
    __shared__ double prow[512];
    __shared__ unsigned cent[NCAP];
    __shared__ int r64i[NRE];
    __shared__ double cval[NRE];
    __shared__ float selv[32];
    __shared__ int seli[32];
    __shared__ int cnt, bstar;

    const double* prg = pw + ((size_t)pset * 1024 + row) * 512;
    const unsigned* crow = candg + ((size_t)q * 1024 + row) * 4096;

    for (int b = tid; b < 1024; b += 256) hist[b] = 0;
    if (tid == 0) { cnt = 0; bstar = -1; }
    if (tid < NRE) r64i[tid] = 0;
    prow[tid] = prg[tid];
    prow[tid + 256] = prg[tid + 256];

    uint4 cv[4];
#pragma unroll
    for (int p = 0; p < 4; ++p) cv[p] = ((const uint4*)crow)[p * 256 + tid];
    __syncthreads();

    // histogram of key>>5 (1024 bins); sentinel 0 entries skipped
#pragma unroll
    for (int p = 0; p < 4; ++p) {
        const unsigned ee[4] = {cv[p].x, cv[p].y, cv[p].z, cv[p].w};
#pragma unroll
        for (int e = 0; e < 4; ++e)
            if (ee[e]) atomicAdd(&hist[ee[e] >> 21], 1u);
    }
    __syncthreads();

    // suffix-scan from the top to find key threshold with >=64 above
    const unsigned h0 = hist[tid * 4], h1 = hist[tid * 4 + 1];
    const unsigned h2 = hist[tid * 4 + 2], h3 = hist[tid * 4 + 3];
    const unsigned l3 = h3, l2 = h2 + l3, l1 = h1 + l2, l0 = h0 + l1;
    pscan[tid] = l0;
    __syncthreads();
    for (int s = 1; s < 256; s <<= 1) {
        const unsigned v = (tid + s < 256) ? pscan[tid + s] : 0u;
        __syncthreads();
        pscan[tid] += v;
        __syncthreads();
    }
    {
        const unsigned above = (tid < 255) ? pscan[tid + 1] : 0u;
        int best = -1;
        if (l0 + above >= 64u) best = tid * 4;
        if (l1 + above >= 64u) best = tid * 4 + 1;
        if (l2 + above >= 64u) best = tid * 4 + 2;
        if (l3 + above >= 64u) best = tid * 4 + 3;
        if (best >= 0) atomicMax(&bstar, best);
    }
    __syncthreads();
    const unsigned kmin = (unsigned)(bstar < 0 ? 1 : bstar) << 5;

    // collect candidates >= kmin
#pragma unroll
    for (int p = 0; p < 4; ++p) {
        const unsigned ee[4] = {cv[p].x, cv[p].y, cv[p].z, cv[p].w};
#pragma unroll
        for (int e = 0; e < 4; ++e) {
            if (ee[e] && (ee[e] >> 16) >= kmin) {
                const int pos = atomicAdd(&cnt, 1);
                if (pos < NCAP) cent[pos] = ee[e];
            }
        }
    }
    __syncthreads();
    const int nc = min(cnt, NCAP);

    // approx-rank on packed u32 desc == (key desc, col asc); keep top NRE
    for (int p = tid; p < nc; p += 256) {
        const unsigned e = cent[p];
        int rr = 0;
        for (int j = 0; j < nc; ++j) rr += (cent[j] > e) ? 1 : 0;
        if (rr < NRE) r64i[rr] = 16383 - (int)(e & 0xFFFFu);
    }
    __syncthreads();

    // exact fp64 recompute against combined fp32 weights (single dot)
    const float* wsel = (q & 1) ? wrf : wcf;
    const int w = tid >> 6, lane = tid & 63;
    for (int c = w; c < NRE; c += 4) {
        const int idx = r64i[c];
        const float4* rp4 = (const float4*)(wsel + (size_t)idx * 512);
        const float4 r0 = rp4[lane * 2], r1 = rp4[lane * 2 + 1];
        const double* pv = prow + lane * 8;
        double aR = pv[0] * (double)r0.x + pv[1] * (double)r0.y + pv[2] * (double)r0.z + pv[3] * (double)r0.w
                  + pv[4] * (double)r1.x + pv[5] * (double)r1.y + pv[6] * (double)r1.z + pv[7] * (double)r1.w;
        for (int sh = 32; sh > 0; sh >>= 1) aR += __shfl_down(aR, sh);
        if (lane == 0) cval[c] = aR;
    }
    __syncthreads();

    // exact top-32 by (|v| desc, idx asc) -- matches lax.top_k tie semantics
    if (tid < NRE) {
        const double av = fabs(cval[tid]);
        const int mi = r64i[tid];
        int rr = 0;
        for (int j = 0; j < NRE; ++j) {
            const double aj = fabs(cval[j]);
            rr += (aj > av || (aj == av && r64i[j] < mi)) ? 1 : 0;
        }
        if (rr < 32) { selv[rr] = (float)cval[tid]; seli[rr] = mi; }
    }
    __syncthreads();
    if (tid < 32) {
        const size_t sb = ((size_t)q * 1024 + row) * 32 + tid;
        selvw[sb] = selv[tid];
        seliw[sb] = seli[tid];
    }

    // rep = sum_k v_k * atoms[idx_k]
    double a0 = 0, a1 = 0;
    for (int k = 0; k < 32; ++k) {
        const double v = (double)selv[k];
        const float* ar = atoms + (size_t)seli[k] * 512;
        a0 += v * (double)ar[tid];
        a1 += v * (double)ar[tid + 256];
    }
    float* rp = repw + ((size_t)q * 1024 + row) * 512;
    rp[tid] = (float)a0;
    rp[tid + 256] = (float)a1;
}

// ---------------- K7: zero own sparse rows + fused + heads + scatter -------
__global__ __launch_bounds__(256) void heads_kernel(
    const double* __restrict__ pw, const float* __restrict__ repw,
    const float* __restrict__ chw, const float* __restrict__ chb,
    const float* __restrict__ rhw, const float* __restrict__ rhb,
    const float* __restrict__ selvw, const int* __restrict__ seliw,
    float* __restrict__ out)
{
    const int row = blockIdx.x, s = blockIdx.y;
    const int tid = threadIdx.x;
    __shared__ double fused[512];

    // zero this block's two sparse rows (q = 2s, 2s+1)
    float4* z0 = (float4*)(out + (size_t)OUT_SPARSE + (size_t)(2 * s + 0) * SPARSE_PER + (size_t)row * 16384);
    float4* z1 = (float4*)(out + (size_t)OUT_SPARSE + (size_t)(2 * s + 1) * SPARSE_PER + (size_t)row * 16384);
    const float4 z = {0.f, 0.f, 0.f, 0.f};
#pragma unroll
    for (int i = 0; i < 16; ++i) { z0[i * 256 + tid] = z; z1[i * 256 + tid] = z; }

    const double* pr = pw + ((size_t)s * 1024 + row) * 512;
    const float* rc = repw + ((size_t)(s * 2 + 0) * 1024 + row) * 512;
    const float* rr = repw + ((size_t)(s * 2 + 1) * 1024 + row) * 512;
    for (int d = tid; d < 512; d += 256)
        fused[d] = 0.2 * pr[d] + 0.9 * (double)rc[d] + 0.9 * (double)rr[d];
    __syncthreads();   // zero writes done block-wide; fused visible

    // scatter this row's 64 selected values over the zeroed rows
    if (tid < 64) {
        const int qq = s * 2 + (tid >> 5), k = tid & 31;
        const size_t sb = ((size_t)qq * 1024 + row) * 32 + k;
        out[(size_t)OUT_SPARSE + (size_t)qq * SPARSE_PER + (size_t)row * 16384 + (size_t)seliw[sb]] = selvw[sb];
    }

    const int w = tid >> 6, lane = tid & 63;
    for (int o = w; o < 22; o += 4) {
        const float* hw2 = (o < 16) ? (chw + (size_t)o * 512) : (rhw + (size_t)(o - 16) * 512);
        double acc = 0;
#pragma unroll
        for (int j = 0; j < 8; ++j) acc += fused[lane + 64 * j] * (double)hw2[lane + 64 * j];
        for (int sh = 32; sh > 0; sh >>= 1) acc += __shfl_down(acc, sh);
        if (lane == 0) {
            if (o < 16) out[(s ? 22528 : 0) + row * 16 + o] = (float)(acc + (double)chb[o]);
            else        out[(s ? 38912 : 16384) + row * 6 + (o - 16)] = (float)(acc + (double)rhb[o - 16]);
        }
    }
}

// ---------------------------------------------------------------------------
extern "C" void kernel_launch(void* const* d_in, const int* in_sizes, int n_in,
                              void* d_out, int out_size, void* d_ws, size_t ws_size,
                              hipStream_t stream)
{
    const int*   ctok   = (const int*)d_in[0];
    const int*   ntok   = (const int*)d_in[1];
    const float* emb    = (const float*)d_in[2];
    const float* w1     = (const float*)d_in[3];
    const float* b1     = (const float*)d_in[4];
    const float* w2     = (const float*)d_in[5];
    const float* b2     = (const float*)d_in[6];
    const float* atoms  = (const float*)d_in[7];
    const float* router = (const float*)d_in[8];
    const float* cdelta = (const float*)d_in[9];
    const float* rdelta = (const float*)d_in[10];
    const float* chw    = (const float*)d_in[11];
    const float* chb    = (const float*)d_in[12];
    const float* rhw    = (const float*)d_in[13];
    const float* rhb    = (const float*)d_in[14];
    float* out = (float*)d_out;

    // staging inside the 256 MB sparse-output region (zeroed by heads_kernel)
    float*    wcf   = out + OUT_SPARSE;           // [16384*512] fp32 combined (concept)
    float*    wrf   = wcf + 8388608;              // [16384*512] fp32 combined (relation)
    unsigned* candg = (unsigned*)(wrf + 8388608); // [4*1024*128*32] packed candidates

    // workspace layout (66 MB, identical footprint to R2)
    double*    xw   = (double*)d_ws;              // [2*1024*512] fp64
    double*    hw   = xw + 1048576;               // [2*1024*512] fp64 (dead after enc_gemm#2)
    double*    pw   = hw + 1048576;               // [2*1024*512] fp64
    float*     repw = (float*)(pw + 1048576);     // [4*1024*512] fp32
    _Float16*  pf16 = (_Float16*)(repw + 2097152);// [2*1024*512] fp16
    _Float16*  wcw  = pf16 + 1048576;             // [16384*512] fp16
    _Float16*  wrw  = wcw + 8388608;              // [16384*512] fp16
    float*     selvw = (float*)hw;                // [4*1024*32] reuse dead hw buffer
    int*       seliw = (int*)(selvw + 131072);    // [4*1024*32]

    pool_kernel<<<dim3(1024, 2), 128, 0, stream>>>(ctok, ntok, emb, xw);
    enc_gemm<<<dim3(8, 32), 256, 0, stream>>>(xw, w1, b1, hw, (_Float16*)nullptr, 1);
    enc_gemm<<<dim3(8, 32), 256, 0, stream>>>(hw, w2, b2, pw, pf16, 0);
    combine_kernel<<<8192, 256, 0, stream>>>(router, cdelta, rdelta, wcw, wrw, wcf, wrf);
    approx_gemm<<<dim3(128, 8, 4), 256, 0, stream>>>(pf16, wcw, wrw, candg);
    select_kernel<<<dim3(1024, 4), 256, 0, stream>>>(pw, wcf, wrf, candg, atoms, selvw, seliw, repw);
    heads_kernel<<<dim3(1024, 2), 256, 0, stream>>>(pw, repw, chw, chb, rhw, rhb, selvw, seliw, out);
}